// Round 4
// baseline (3989.939 us; speedup 1.0000x reference)
//
#include <hip/hip_runtime.h>

// LSTMencoder: 2-layer biLSTM, B=256, T=2048, H=32 (4H=128), F=32/64.
// One wave per (batch,dir) chain, persistent over T. ALL per-lane state in
// ext_vector SSA values (no arrays -> no allocas -> no scratch; 512-VGPR
// budget at 1 wave/SIMD). Input dot: f2 chunks -> v_pk_fma_f32. Recurrent
// dot: h broadcast via v_readlane (R2's proven-correct scheme), scalar fma
// with SGPR operand. P = sig(i)*tanh(g) crosses halves via one ds_bpermute.
// Lane l owns gate rows l (i|f) and 64+l (g|o); upper lanes own c,h.

#define T_LEN 2048
#define BATCH 256

typedef float f2  __attribute__((ext_vector_type(2)));
typedef float v16 __attribute__((ext_vector_type(16)));
typedef float v32 __attribute__((ext_vector_type(32)));
typedef float v64 __attribute__((ext_vector_type(64)));

__device__ __forceinline__ float frcp(float x) { return __builtin_amdgcn_rcpf(x); }
__device__ __forceinline__ float rdlane(float v, int k) {
    return __int_as_float(__builtin_amdgcn_readlane(__float_as_int(v), k));
}

#define CH(V,I)   (__builtin_shufflevector((V),(V),2*(I),2*(I)+1))
#define PK(x,w,a) (__builtin_elementwise_fma((x),(w),(a)))

// input-dot chunk: X chunk I, W chunk (I)+(WO), accumulator K
#define DC(X,WA,WB,I,WO,K) \
  aA##K = PK(CH(X,I), CH(WA,(I)+(WO)), aA##K); \
  aB##K = PK(CH(X,I), CH(WB,(I)+(WO)), aB##K);
#define DC4(X,WA,WB,I0,WO) \
  DC(X,WA,WB,(I0)+0,WO,0) DC(X,WA,WB,(I0)+1,WO,1) \
  DC(X,WA,WB,(I0)+2,WO,2) DC(X,WA,WB,(I0)+3,WO,3)
#define DC8(X,WA,WB,I0,WO)  DC4(X,WA,WB,I0,WO) DC4(X,WA,WB,(I0)+4,WO)
#define DC32(X,WA,WB) \
  DC8(X,WA,WB,0,0) DC8(X,WA,WB,8,0) DC8(X,WA,WB,16,0) DC8(X,WA,WB,24,0)

// recurrent dot: h(t-1) lives in upper lanes of hPrev; broadcast via readlane
#define RD(K) { float hk = rdlane(hPrev, 32+(K)); \
                accA = fmaf(hk, uA[K], accA); accB = fmaf(hk, uB[K], accB); }
#define RD4(K)  RD(K) RD((K)+1) RD((K)+2) RD((K)+3)
#define RD16(K) RD4(K) RD4((K)+4) RD4((K)+8) RD4((K)+12)
#define RD32    RD16(0) RD16(16)

// epilogue: nonlinearities -> c,h update -> store; updates hPrev
#define TAIL() \
  f2 rA2 = (aA0+aA1)+(aA2+aA3); float accA = rA2[0]+rA2[1]; \
  f2 rB2 = (aB0+aB1)+(aB2+aB3); float accB = rB2[0]+rB2[1]; \
  RD32 \
  float sA = frcp(1.f + __expf(-accA));                   /* sig(i)|sig(f) */ \
  float sB = fmaf(sBa, frcp(1.f + __expf(accB*mB)), sBb); /* tanh(g)|sig(o) */ \
  float Pv = sA*sB; \
  int Pri = __builtin_amdgcn_ds_bpermute(bpa, __float_as_int(Pv)); \
  c = fmaf(sA, c, __int_as_float(Pri));                   /* upper: sig(f)c+P */ \
  float tc = fmaf(2.f, frcp(1.f + __expf(-2.f*c)), -1.f); \
  float hj = sB*tc;                                       /* upper: sig(o)tanh */ \
  if (up) *pSt = hj; \
  pSt += stStep; \
  hPrev = hj;

__global__ __launch_bounds__(64, 1) void lstm_l0(
        const float* __restrict__ OS, const float* __restrict__ IS,
        const float* __restrict__ Wih, const float* __restrict__ Whh,
        const float* __restrict__ bih, const float* __restrict__ bhh,
        float* __restrict__ h1out)
{
    const int l = threadIdx.x, b = blockIdx.x, dir = blockIdx.y;
    const int u = l & 31; const bool up = (l >= 32);
    const int gA = l, gB = 64 + l;

    v32 wA = *(const v32*)(Wih + ((size_t)dir*128 + gA)*32);
    v32 wB = *(const v32*)(Wih + ((size_t)dir*128 + gB)*32);
    v32 uA = *(const v32*)(Whh + ((size_t)dir*128 + gA)*32);
    v32 uB = *(const v32*)(Whh + ((size_t)dir*128 + gB)*32);
    const float biasA = bih[dir*128+gA] + bhh[dir*128+gA];
    const float biasB = bih[dir*128+gB] + bhh[dir*128+gB];

    const int te0 = dir ? (T_LEN-1) : 0;
    const float* pOS = OS + ((size_t)b*T_LEN + te0)*16;
    const float* pIS = IS + ((size_t)b*T_LEN + (T_LEN-1 - te0))*16;
    const ptrdiff_t osStep = dir ? -16 : 16, isStep = -osStep;
    float* pSt = h1out + (size_t)te0*(BATCH*64) + b*64 + dir*32 + u;
    const ptrdiff_t stStep = dir ? -(ptrdiff_t)(BATCH*64) : (BATCH*64);

    const float mB  = up ? -1.f : -2.f;
    const float sBa = up ?  1.f :  2.f;
    const float sBb = up ?  0.f : -1.f;
    const int   bpa = (l ^ 32) << 2;

    float c = 0.f, hPrev = 0.f;
    int np = 0;
    v16 XoA, XiA, XoB, XiB, XoC, XiC, XoD, XiD;

#define L0_LOAD(SUF) \
    Xo##SUF = *(const v16*)pOS; Xi##SUF = *(const v16*)pIS; \
    if (np < T_LEN-1) { pOS += osStep; pIS += isStep; ++np; }

#define L0_STEP(SUF) do { \
    f2 aA0={biasA,0.f}, aA1={0.f,0.f}, aA2={0.f,0.f}, aA3={0.f,0.f}; \
    f2 aB0={biasB,0.f}, aB1={0.f,0.f}, aB2={0.f,0.f}, aB3={0.f,0.f}; \
    DC8(Xo##SUF, wA, wB, 0, 0) \
    DC8(Xi##SUF, wA, wB, 0, 8) \
    L0_LOAD(SUF)                  /* prefetch t+4 */ \
    TAIL() \
} while (0)

    L0_LOAD(A); L0_LOAD(B); L0_LOAD(C); L0_LOAD(D);
#pragma unroll 1
    for (int tt = 0; tt < T_LEN; tt += 4) {
        L0_STEP(A); L0_STEP(B); L0_STEP(C); L0_STEP(D);
    }
#undef L0_LOAD
#undef L0_STEP
}

__global__ __launch_bounds__(64, 1) void lstm_l1(
        const float* __restrict__ h1in,
        const float* __restrict__ Wih, const float* __restrict__ Whh,
        const float* __restrict__ bih, const float* __restrict__ bhh,
        float* __restrict__ outp)
{
    const int l = threadIdx.x, b = blockIdx.x, dir = blockIdx.y;
    const int u = l & 31; const bool up = (l >= 32);
    const int gA = l, gB = 64 + l;

    v64 wA = *(const v64*)(Wih + ((size_t)dir*128 + gA)*64);
    v64 wB = *(const v64*)(Wih + ((size_t)dir*128 + gB)*64);
    v32 uA = *(const v32*)(Whh + ((size_t)dir*128 + gA)*32);
    v32 uB = *(const v32*)(Whh + ((size_t)dir*128 + gB)*32);
    const float biasA = bih[dir*128+gA] + bhh[dir*128+gA];
    const float biasB = bih[dir*128+gB] + bhh[dir*128+gB];

    const int te0 = dir ? (T_LEN-1) : 0;
    const float* pH1 = h1in + ((size_t)te0*BATCH + b)*64;
    const ptrdiff_t hStep = dir ? -(ptrdiff_t)(BATCH*64) : (BATCH*64);
    float* pSt = outp + ((size_t)b*T_LEN + te0)*64 + dir*32 + u;
    const ptrdiff_t stStep = dir ? -64 : 64;

    const float mB  = up ? -1.f : -2.f;
    const float sBa = up ?  1.f :  2.f;
    const float sBb = up ?  0.f : -1.f;
    const int   bpa = (l ^ 32) << 2;

    float c = 0.f, hPrev = 0.f;
    int np = 0;
    v64 XcA, XcB;

#define L1_LOAD(SUF) \
    Xc##SUF = *(const v64*)pH1; \
    if (np < T_LEN-1) { pH1 += hStep; ++np; }

#define L1_STEP(SUF) do { \
    f2 aA0={biasA,0.f}, aA1={0.f,0.f}, aA2={0.f,0.f}, aA3={0.f,0.f}; \
    f2 aB0={biasB,0.f}, aB1={0.f,0.f}, aB2={0.f,0.f}, aB3={0.f,0.f}; \
    DC32(Xc##SUF, wA, wB) \
    L1_LOAD(SUF)                  /* prefetch t+2 */ \
    TAIL() \
} while (0)

    L1_LOAD(A); L1_LOAD(B);
#pragma unroll 1
    for (int tt = 0; tt < T_LEN; tt += 2) { L1_STEP(A); L1_STEP(B); }
#undef L1_LOAD
#undef L1_STEP
}

extern "C" void kernel_launch(void* const* d_in, const int* in_sizes, int n_in,
                              void* d_out, int out_size, void* d_ws, size_t ws_size,
                              hipStream_t stream) {
    const float* OS    = (const float*)d_in[0];
    const float* IS    = (const float*)d_in[1];
    const float* W_ih0 = (const float*)d_in[2];
    const float* W_hh0 = (const float*)d_in[3];
    const float* b_ih0 = (const float*)d_in[4];
    const float* b_hh0 = (const float*)d_in[5];
    const float* W_ih1 = (const float*)d_in[6];
    const float* W_hh1 = (const float*)d_in[7];
    const float* b_ih1 = (const float*)d_in[8];
    const float* b_hh1 = (const float*)d_in[9];
    float* out = (float*)d_out;
    float* h1  = (float*)d_ws;       // [T, B, 64] f32 = 128 MiB intermediate

    dim3 grid(BATCH, 2), block(64);
    hipLaunchKernelGGL(lstm_l0, grid, block, 0, stream,
                       OS, IS, W_ih0, W_hh0, b_ih0, b_hh0, h1);
    hipLaunchKernelGGL(lstm_l1, grid, block, 0, stream,
                       h1, W_ih1, W_hh1, b_ih1, b_hh1, out);
}